// Round 1
// baseline (569.296 us; speedup 1.0000x reference)
//
#include <hip/hip_runtime.h>
#include <cstdint>

// ShortTermLSTM on MI355X: batched LSTM via f16 MFMA with hi/lo split-precision
// recurrence.
//
// gates[S=16,400] = A[16,128] x B[128,400] per timestep, where
//   A cols   0.. 99 : h (hi part in A_hi, lo part in A_lo)  -> B rows = f16(W_hh)
//   A cols 100..103 : x_hi in A_hi, x_lo in A_lo            -> B rows = f16(W_ih)       (=W_hi)
//   A cols 104..107 : 0 in A_hi,    x_hi in A_lo            -> B rows = f16(W_ih-W_hi)  (=W_lo)
//   A col  108      : 1 in A_hi, 0 in A_lo                  -> B row  = f16(b)          (=b_hi)
//   A col  109      : 0 in A_hi, 1 in A_lo                  -> B row  = f16(b-b_hi)     (=b_lo)
//   A cols 110..127 : 0
// gates = (A_hi + A_lo) x B computed as two MFMAs sharing B fragments (in VGPRs).
// c kept in fp32 registers; nonlinearities in fp32 VALU; only residual error is
// the dropped h*W_hh_lo term (~6e-5/step with f16 weights).

#define H_UNITS 100
#define T_STEPS 128
#define S_BLK   16
#define NSEQ    12288
#define NBLK    (NSEQ / S_BLK)   // 768
#define NCOL    400
#define NTILE   25               // 400 / 16
#define KSTR    136              // LDS A row stride (ushorts): 272B -> 2-way-only bank aliasing
#define GPAD    20               // gates LDS row stride (floats): 80B -> 2-way-only
#define XSTR    516              // x stage per-seq stride (floats): breaks 512-stride conflicts

typedef __attribute__((ext_vector_type(8))) _Float16 halfx8;
typedef __attribute__((ext_vector_type(8))) unsigned short ushortx8;
typedef __attribute__((ext_vector_type(4))) float floatx4;

__device__ __forceinline__ unsigned short f32_to_f16u(float x) {
    _Float16 h = (_Float16)x;                       // v_cvt_f16_f32 (RNE)
    return __builtin_bit_cast(unsigned short, h);
}
__device__ __forceinline__ float f16u_to_f32(unsigned short u) {
    _Float16 h = __builtin_bit_cast(_Float16, u);
    return (float)h;
}
__device__ __forceinline__ float fsigm(float x) {
    return __builtin_amdgcn_rcpf(1.0f + __expf(-x));
}
__device__ __forceinline__ float ftanh(float x) {
    // 1 - 2/(e^{2x}+1); exp->inf handled correctly (rcp(inf)=0)
    return 1.0f - 2.0f * __builtin_amdgcn_rcpf(1.0f + __expf(2.0f * x));
}

// ---------------------------------------------------------------------------
// Prep: pack B into MFMA B-fragment order: Bpack[tile][kc][lane][j] (8 f16 = 16B)
//   n = tile*16 + (lane&15),  k = kc*32 + (lane>>4)*8 + j
// ---------------------------------------------------------------------------
__global__ void lstm_prep_pack(const float* __restrict__ W_ih,
                               const float* __restrict__ W_hh,
                               const float* __restrict__ b_ih,
                               const float* __restrict__ b_hh,
                               ushortx8* __restrict__ Bpack) {
    int t = blockIdx.x * 256 + threadIdx.x;   // (tile,kc,lane) flattened: 25*4*64 = 6400
    if (t >= NTILE * 4 * 64) return;
    int lane = t & 63;
    int kc   = (t >> 6) & 3;
    int tile = t >> 8;
    int n  = tile * 16 + (lane & 15);
    int k0 = kc * 32 + ((lane >> 4) & 3) * 8;
    ushortx8 v;
#pragma unroll
    for (int j = 0; j < 8; ++j) {
        int k = k0 + j;
        unsigned short w = 0;
        if (k < 100) {
            w = f32_to_f16u(W_hh[n * 100 + k]);
        } else if (k < 104) {
            w = f32_to_f16u(W_ih[n * 4 + (k - 100)]);
        } else if (k < 108) {
            float wf = W_ih[n * 4 + (k - 104)];
            unsigned short hi = f32_to_f16u(wf);
            w = f32_to_f16u(wf - f16u_to_f32(hi));
        } else if (k == 108) {
            float b = b_ih[n] + b_hh[n];
            w = f32_to_f16u(b);
        } else if (k == 109) {
            float b = b_ih[n] + b_hh[n];
            unsigned short hi = f32_to_f16u(b);
            w = f32_to_f16u(b - f16u_to_f32(hi));
        }
        v[j] = w;
    }
    Bpack[t] = v;
}

// ---------------------------------------------------------------------------
// Main: one block = 16 sequences, full T loop. 4 waves; wave w owns N-tiles
// {w, w+4, ..., w+24 (wave0 only)}. B frags persist in VGPRs (~112/wave).
// ---------------------------------------------------------------------------
__global__ void __launch_bounds__(256, 2)
lstm_main(const float* __restrict__ x, const ushortx8* __restrict__ Bpack,
          float* __restrict__ out) {
    __shared__ __align__(16) float          s_x[S_BLK * XSTR];      // 33024 B
    __shared__ __align__(16) unsigned short s_A[2 * 16 * KSTR];     //  8704 B (A_hi | A_lo)
    __shared__ __align__(16) float          s_g[NCOL * GPAD];       // 32000 B

    const int tid  = threadIdx.x;
    const int lane = tid & 63;
    const int wave = tid >> 6;
    const int seq0 = blockIdx.x * S_BLK;
    const int m    = lane & 15;
    const int quad = lane >> 4;

    // ---- B fragments: global -> VGPRs, once
    halfx8 bfrag[7][4];
#pragma unroll
    for (int it = 0; it < 7; ++it) {
        int tile = wave + it * 4;
        if (tile < NTILE) {
#pragma unroll
            for (int kc = 0; kc < 4; ++kc)
                bfrag[it][kc] = __builtin_bit_cast(halfx8, Bpack[(tile * 4 + kc) * 64 + lane]);
        }
    }

    // ---- stage this block's x [16][128][4] fp32 into LDS (coalesced float4)
    {
        const float4* xg = (const float4*)(x + (size_t)seq0 * (T_STEPS * 4));
        for (int i = tid; i < S_BLK * T_STEPS; i += 256) {   // 2048 float4
            float4 v = xg[i];
            int s = i >> 7, off = (i & 127) << 2;
            *(float4*)&s_x[s * XSTR + off] = v;
        }
    }
    // ---- zero A (h(0)=0, pad cols 0)
    for (int i = tid; i < (2 * 16 * KSTR) / 2; i += 256)
        ((unsigned int*)s_A)[i] = 0u;
    __syncthreads();
    // ---- init x(t=0) cols + constant bias-select cols
    if (tid < 160) {
        int s = tid & 15, cc = tid >> 4;   // cc 0..9
        if (cc < 8) {
            float xv = s_x[s * XSTR + (cc & 3)];
            unsigned short hi = f32_to_f16u(xv);
            if (cc < 4) {
                s_A[s * KSTR + 100 + cc]        = hi;                              // A_hi = x_hi
                s_A[(16 + s) * KSTR + 100 + cc] = f32_to_f16u(xv - f16u_to_f32(hi)); // A_lo = x_lo
            } else {
                s_A[(16 + s) * KSTR + 100 + cc] = hi;                              // A_lo = x_hi (W_lo rows)
            }
        } else if (cc == 8) {
            s_A[s * KSTR + 108] = 0x3C00;          // A_hi col108 = 1.0 (bias hi)
        } else {
            s_A[(16 + s) * KSTR + 109] = 0x3C00;   // A_lo col109 = 1.0 (bias lo)
        }
    }

    float c_reg[7];
#pragma unroll
    for (int u = 0; u < 7; ++u) c_reg[u] = 0.0f;

    const unsigned short* aHi = &s_A[m * KSTR + quad * 8];
    const unsigned short* aLo = &s_A[(16 + m) * KSTR + quad * 8];

    for (int t = 0; t < T_STEPS; ++t) {
        __syncthreads();   // A(t) ready
        halfx8 ah[4], al[4];
#pragma unroll
        for (int kc = 0; kc < 4; ++kc) {
            ah[kc] = *(const halfx8*)(aHi + kc * 32);   // ds_read_b128
            al[kc] = *(const halfx8*)(aLo + kc * 32);
        }
#pragma unroll
        for (int it = 0; it < 7; ++it) {
            int tile = wave + it * 4;
            if (tile < NTILE) {
                floatx4 acc = {0.0f, 0.0f, 0.0f, 0.0f};
#pragma unroll
                for (int kc = 0; kc < 4; ++kc) {
                    acc = __builtin_amdgcn_mfma_f32_16x16x32_f16(ah[kc], bfrag[it][kc], acc, 0, 0, 0);
                    acc = __builtin_amdgcn_mfma_f32_16x16x32_f16(al[kc], bfrag[it][kc], acc, 0, 0, 0);
                }
                // C/D layout: col = lane&15, row(seq) = quad*4 + r  -> [n][s] layout, b128 write
                *(floatx4*)&s_g[(tile * 16 + m) * GPAD + quad * 4] = acc;
            }
        }
        __syncthreads();   // gates ready

        const bool last = (t == T_STEPS - 1);
#pragma unroll
        for (int u = 0; u < 7; ++u) {
            int idx = tid + u * 256;
            if (idx < 1600) {               // (s, j) unit update
                int s = idx & 15, j = idx >> 4;
                float gi = s_g[j * GPAD + s];
                float gf = s_g[(100 + j) * GPAD + s];
                float gg = s_g[(200 + j) * GPAD + s];
                float go = s_g[(300 + j) * GPAD + s];
                float c  = fsigm(gf) * c_reg[u] + fsigm(gi) * ftanh(gg);
                c_reg[u] = c;
                float h  = fsigm(go) * ftanh(c);
                if (!last) {
                    unsigned short hi = f32_to_f16u(h);
                    s_A[s * KSTR + j]        = hi;                                  // h_hi
                    s_A[(16 + s) * KSTR + j] = f32_to_f16u(h - f16u_to_f32(hi));    // h_lo
                } else {
                    out[(size_t)(seq0 + s) * H_UNITS + j] = h;   // final hidden state
                }
            } else if (idx < 1728) {        // refresh x(t+1) cols 100..107
                if (!last) {
                    int kk = idx - 1600;
                    int s = kk & 15, cc = kk >> 4;   // cc 0..7
                    float xv = s_x[s * XSTR + (t + 1) * 4 + (cc & 3)];
                    unsigned short hi = f32_to_f16u(xv);
                    if (cc < 4) {
                        s_A[s * KSTR + 100 + cc]        = hi;
                        s_A[(16 + s) * KSTR + 100 + cc] = f32_to_f16u(xv - f16u_to_f32(hi));
                    } else {
                        s_A[(16 + s) * KSTR + 100 + cc] = hi;
                    }
                }
            }
        }
    }
}

extern "C" void kernel_launch(void* const* d_in, const int* in_sizes, int n_in,
                              void* d_out, int out_size, void* d_ws, size_t ws_size,
                              hipStream_t stream) {
    const float* x    = (const float*)d_in[0];   // [4096,3,128,4]
    const float* W_ih = (const float*)d_in[1];   // [400,4]
    const float* W_hh = (const float*)d_in[2];   // [400,100]
    const float* b_ih = (const float*)d_in[3];   // [400]
    const float* b_hh = (const float*)d_in[4];   // [400]
    ushortx8* Bpack = (ushortx8*)d_ws;           // 25*4*64*16 B = 102,400 B

    lstm_prep_pack<<<25, 256, 0, stream>>>(W_ih, W_hh, b_ih, b_hh, Bpack);
    lstm_main<<<NBLK, 256, 0, stream>>>(x, Bpack, (float*)d_out);
}

// Round 4
// 444.101 us; speedup vs baseline: 1.2819x; 1.2819x over previous
//
#include <hip/hip_runtime.h>
#include <cstdint>

// ShortTermLSTM on MI355X: batched LSTM via f16 MFMA with hi/lo split-precision
// recurrence.
// R1 (verified, 569us): 4x 16x16x32 MFMA pairs, K=128 zero-padded, absmax 1.95e-3.
// R2/R3 (failed): legacy 16x16x16f16 for kc3 — its B-fragment layout is NOT
//   k=quad*4+j (absmax 0.61). Reverted.
// R4: R1 numerics + occupancy push: s_x removed (global x prefetch riding the
//   MFMA phase), LDS 40,704 B, launch_bounds(256,3) -> 3 blocks/CU, all 768
//   blocks co-resident.
//
// gates[S=16,400] = A[16,128] x B[128,400] per timestep:
//   A cols   0.. 99 : h   (hi in A_hi, lo in A_lo)    -> B = f16(W_hh)
//   A cols 100..103 : x_hi in A_hi, x_lo in A_lo      -> B = f16(W_ih)      (=W_hi)
//   A cols 104..107 : 0 in A_hi,    x_hi in A_lo      -> B = f16(W_ih-W_hi) (=W_lo)
//   A col  108      : 1 in A_hi, 0 in A_lo            -> B = f16(b)         (=b_hi)
//   A col  109      : 0 in A_hi, 1 in A_lo            -> B = f16(b-b_hi)    (=b_lo)
//   A cols 110..127 : 0 (zeroed once, never written)
// c in fp32 registers; nonlinearities fp32 VALU; residual error = dropped
// h*W_hh_lo term (~6e-5/step).

#define H_UNITS 100
#define T_STEPS 128
#define S_BLK   16
#define NSEQ    12288
#define NBLK    (NSEQ / S_BLK)   // 768
#define NCOL    400
#define NTILE   25               // 400 / 16
#define KSTR    136              // LDS A row stride (ushorts): 272B -> 2-way-only bank aliasing
#define GPAD    20               // gates LDS row stride (floats): 80B -> low-way bank aliasing

typedef __attribute__((ext_vector_type(8))) _Float16 halfx8;
typedef __attribute__((ext_vector_type(8))) unsigned short ushortx8;
typedef __attribute__((ext_vector_type(4))) float floatx4;

__device__ __forceinline__ unsigned short f32_to_f16u(float x) {
    _Float16 h = (_Float16)x;                       // v_cvt_f16_f32 (RNE)
    return __builtin_bit_cast(unsigned short, h);
}
__device__ __forceinline__ float f16u_to_f32(unsigned short u) {
    _Float16 h = __builtin_bit_cast(_Float16, u);
    return (float)h;
}
__device__ __forceinline__ float fsigm(float x) {
    return __builtin_amdgcn_rcpf(1.0f + __expf(-x));
}
__device__ __forceinline__ float ftanh(float x) {
    // 1 - 2/(e^{2x}+1); exp->inf handled correctly (rcp(inf)=0)
    return 1.0f - 2.0f * __builtin_amdgcn_rcpf(1.0f + __expf(2.0f * x));
}

// ---------------------------------------------------------------------------
// Prep: pack B into MFMA B-fragment order: Bpack[tile][kc][lane][j] (8 f16 = 16B)
//   n = tile*16 + (lane&15),  k = kc*32 + (lane>>4)*8 + j      (VERIFIED in R1)
// ---------------------------------------------------------------------------
__global__ void lstm_prep_pack(const float* __restrict__ W_ih,
                               const float* __restrict__ W_hh,
                               const float* __restrict__ b_ih,
                               const float* __restrict__ b_hh,
                               ushortx8* __restrict__ Bpack) {
    int t = blockIdx.x * 256 + threadIdx.x;   // (tile,kc,lane) flattened: 25*4*64 = 6400
    if (t >= NTILE * 4 * 64) return;
    int lane = t & 63;
    int kc   = (t >> 6) & 3;
    int tile = t >> 8;
    int n  = tile * 16 + (lane & 15);
    int k0 = kc * 32 + ((lane >> 4) & 3) * 8;
    ushortx8 v;
#pragma unroll
    for (int j = 0; j < 8; ++j) {
        int k = k0 + j;
        unsigned short w = 0;
        if (k < 100) {
            w = f32_to_f16u(W_hh[n * 100 + k]);
        } else if (k < 104) {
            w = f32_to_f16u(W_ih[n * 4 + (k - 100)]);
        } else if (k < 108) {
            float wf = W_ih[n * 4 + (k - 104)];
            unsigned short hi = f32_to_f16u(wf);
            w = f32_to_f16u(wf - f16u_to_f32(hi));
        } else if (k == 108) {
            float b = b_ih[n] + b_hh[n];
            w = f32_to_f16u(b);
        } else if (k == 109) {
            float b = b_ih[n] + b_hh[n];
            unsigned short hi = f32_to_f16u(b);
            w = f32_to_f16u(b - f16u_to_f32(hi));
        }
        v[j] = w;
    }
    Bpack[t] = v;
}

// ---------------------------------------------------------------------------
// Main: one block = 16 sequences, full T loop. 4 waves; wave w owns N-tiles
// {w, w+4, ...}. B frags persist in regs (112, unified VGPR/AGPR file).
// launch_bounds(256,3): 3 blocks/CU -> all 768 blocks co-resident.
// ---------------------------------------------------------------------------
__global__ void __launch_bounds__(256, 3)
lstm_main(const float* __restrict__ x, const ushortx8* __restrict__ Bpack,
          float* __restrict__ out) {
    __shared__ __align__(16) unsigned short s_A[2 * 16 * KSTR];     //  8704 B (A_hi | A_lo)
    __shared__ __align__(16) float          s_g[NCOL * GPAD];       // 32000 B

    const int tid  = threadIdx.x;
    const int lane = tid & 63;
    const int wave = tid >> 6;
    const int seq0 = blockIdx.x * S_BLK;
    const int m    = lane & 15;
    const int quad = lane >> 4;

    // ---- B fragments: global -> regs, once
    halfx8 bfrag[7][4];
#pragma unroll
    for (int it = 0; it < 7; ++it) {
        int tile = wave + it * 4;
        if (tile < NTILE) {
#pragma unroll
            for (int kc = 0; kc < 4; ++kc)
                bfrag[it][kc] = __builtin_bit_cast(halfx8, Bpack[(tile * 4 + kc) * 64 + lane]);
        }
    }

    // refresh-thread x pointer (valid for tid < 128): (s = tid&15, cc = tid>>4)
    const int rs = tid & 15, rc = tid >> 4;
    const float* xb = x + (size_t)(seq0 + rs) * (T_STEPS * 4) + (rc & 3);

    // ---- zero A (h(0)=0, pad cols 110..127 stay 0 forever)
    for (int i = tid; i < (2 * 16 * KSTR) / 2; i += 256)
        ((unsigned int*)s_A)[i] = 0u;
    float x0 = 0.0f;
    if (tid < 128) x0 = xb[0];
    __syncthreads();
    // ---- init x(t=0) cols + constant bias-select cols
    if (tid < 128) {
        unsigned short hi = f32_to_f16u(x0);
        if (rc < 4) {
            s_A[rs * KSTR + 100 + rc]        = hi;                                // A_hi = x_hi
            s_A[(16 + rs) * KSTR + 100 + rc] = f32_to_f16u(x0 - f16u_to_f32(hi)); // A_lo = x_lo
        } else {
            s_A[(16 + rs) * KSTR + 100 + rc] = hi;                                // A_lo = x_hi (W_lo rows)
        }
    } else if (tid < 144) {
        s_A[(tid - 128) * KSTR + 108] = 0x3C00;        // A_hi col108 = 1.0 (bias hi)
    } else if (tid < 160) {
        s_A[(16 + tid - 144) * KSTR + 109] = 0x3C00;   // A_lo col109 = 1.0 (bias lo)
    }

    float c_reg[6];
#pragma unroll
    for (int u = 0; u < 6; ++u) c_reg[u] = 0.0f;
    float c6 = 0.0f;

    const unsigned short* aHi = &s_A[m * KSTR + quad * 8];
    const unsigned short* aLo = &s_A[(16 + m) * KSTR + quad * 8];

    const int us = tid & 15;     // epilogue unit s
    const int j0 = tid >> 4;     // epilogue unit j base (j = j0 + 16u)

    for (int t = 0; t < T_STEPS; ++t) {
        // prefetch x(t+1) — issued before the MFMA phase to hide latency
        float xnext = 0.0f;
        if (tid < 128) {
            int tn = t + 1; if (tn > T_STEPS - 1) tn = T_STEPS - 1;
            xnext = xb[tn * 4];
        }
        __syncthreads();   // A(t) ready
        halfx8 ah[4], al[4];
#pragma unroll
        for (int kc = 0; kc < 4; ++kc) {
            ah[kc] = *(const halfx8*)(aHi + kc * 32);   // ds_read_b128
            al[kc] = *(const halfx8*)(aLo + kc * 32);
        }
#pragma unroll
        for (int it = 0; it < 7; ++it) {
            int tile = wave + it * 4;
            if (tile < NTILE) {
                floatx4 acc = {0.0f, 0.0f, 0.0f, 0.0f};
#pragma unroll
                for (int kc = 0; kc < 4; ++kc) {
                    acc = __builtin_amdgcn_mfma_f32_16x16x32_f16(ah[kc], bfrag[it][kc], acc, 0, 0, 0);
                    acc = __builtin_amdgcn_mfma_f32_16x16x32_f16(al[kc], bfrag[it][kc], acc, 0, 0, 0);
                }
                // C/D layout: col(n-within-tile) = lane&15, row(seq) = quad*4 + r
                *(floatx4*)&s_g[(tile * 16 + m) * GPAD + quad * 4] = acc;
            }
        }
        __syncthreads();   // gates ready

        const bool last = (t == T_STEPS - 1);
#pragma unroll
        for (int u = 0; u < 6; ++u) {
            int j = j0 + u * 16;              // j in 0..95, all threads unconditional
            float gi = s_g[j * GPAD + us];
            float gf = s_g[(100 + j) * GPAD + us];
            float gg = s_g[(200 + j) * GPAD + us];
            float go = s_g[(300 + j) * GPAD + us];
            float c  = fsigm(gf) * c_reg[u] + fsigm(gi) * ftanh(gg);
            c_reg[u] = c;
            float h  = fsigm(go) * ftanh(c);
            if (!last) {
                unsigned short hi = f32_to_f16u(h);
                s_A[us * KSTR + j]        = hi;                                 // h_hi
                s_A[(16 + us) * KSTR + j] = f32_to_f16u(h - f16u_to_f32(hi));   // h_lo
            } else {
                out[(size_t)(seq0 + us) * H_UNITS + j] = h;
            }
        }
        if (tid >= 192) {                     // units j = 96..99
            int d = tid - 192;
            int s = d & 15, j = 96 + (d >> 4);
            float gi = s_g[j * GPAD + s];
            float gf = s_g[(100 + j) * GPAD + s];
            float gg = s_g[(200 + j) * GPAD + s];
            float go = s_g[(300 + j) * GPAD + s];
            float c  = fsigm(gf) * c6 + fsigm(gi) * ftanh(gg);
            c6 = c;
            float h  = fsigm(go) * ftanh(c);
            if (!last) {
                unsigned short hi = f32_to_f16u(h);
                s_A[s * KSTR + j]        = hi;
                s_A[(16 + s) * KSTR + j] = f32_to_f16u(h - f16u_to_f32(hi));
            } else {
                out[(size_t)(seq0 + s) * H_UNITS + j] = h;
            }
        }
        if (tid < 128 && !last) {             // refresh x(t+1) cols 100..107
            unsigned short hi = f32_to_f16u(xnext);
            if (rc < 4) {
                s_A[rs * KSTR + 100 + rc]        = hi;
                s_A[(16 + rs) * KSTR + 100 + rc] = f32_to_f16u(xnext - f16u_to_f32(hi));
            } else {
                s_A[(16 + rs) * KSTR + 100 + rc] = hi;
            }
        }
    }
}

extern "C" void kernel_launch(void* const* d_in, const int* in_sizes, int n_in,
                              void* d_out, int out_size, void* d_ws, size_t ws_size,
                              hipStream_t stream) {
    const float* x    = (const float*)d_in[0];   // [4096,3,128,4]
    const float* W_ih = (const float*)d_in[1];   // [400,4]
    const float* W_hh = (const float*)d_in[2];   // [400,100]
    const float* b_ih = (const float*)d_in[3];   // [400]
    const float* b_hh = (const float*)d_in[4];   // [400]
    ushortx8* Bpack = (ushortx8*)d_ws;           // 25*4*64*16 B = 102,400 B

    lstm_prep_pack<<<25, 256, 0, stream>>>(W_ih, W_hh, b_ih, b_hh, Bpack);
    lstm_main<<<NBLK, 256, 0, stream>>>(x, Bpack, (float*)d_out);
}

// Round 5
// 369.649 us; speedup vs baseline: 1.5401x; 1.2014x over previous
//
#include <hip/hip_runtime.h>
#include <cstdint>

// ShortTermLSTM on MI355X: batched LSTM via f16 MFMA.
// R1 (569us): 4x 16x16x32 MFMA hi/lo pairs, K=128, absmax 1.95e-3.
// R2/R3 (failed): legacy 16x16x16f16 B-layout is NOT k=quad*4+j. Reverted.
// R4 (444us): s_x removed (global x prefetch), launch_bounds(256,3),
//   3 blocks/CU, all 768 blocks co-resident. VALU 51% / MFMA 32.5%.
// R5: h stored f16-only (drop h_lo MFMA path: kc0..2 of A_lo are all-zero ->
//   5 MFMAs/tile instead of 8; error grows ~sqrt(2), measured margin 4x).
//   GPAD 20->24: epilogue gate-read banks form two exact 16-bank partitions
//   (perfect 2-way, free) instead of 3-way.
//
// gates[S=16,400] = A[16,128] x B[128,400] per timestep:
//   A_hi cols   0.. 99 : f16(h)                 -> B = f16(W_hh)
//   A_hi cols 100..103 : x_hi                   -> B = f16(W_ih)      (=W_hi)
//   A_lo cols 104..107 : x_hi (W_lo route)      -> B = f16(W_ih-W_hi) (=W_lo)
//   A_lo cols 100..103 : x_lo                   -> B = f16(W_ih)
//   A_hi col  108      : 1.0                    -> B = f16(b)         (=b_hi)
//   A_lo col  109      : 1.0                    -> B = f16(b-b_hi)    (=b_lo)
//   all other cols 0 (zeroed once, never written; A_lo cols 0..99 stay 0)
// Per tile: 4 MFMAs on A_hi (kc0..3) + 1 MFMA on A_lo (kc3 only).
// c in fp32 registers; nonlinearities fp32 VALU.

#define H_UNITS 100
#define T_STEPS 128
#define S_BLK   16
#define NSEQ    12288
#define NBLK    (NSEQ / S_BLK)   // 768
#define NCOL    400
#define NTILE   25               // 400 / 16
#define KSTR    136              // LDS A row stride (ushorts): 8-phase-ideal b128 reads
#define GPAD    24               // gates LDS row stride (floats): perfect 2-way epilogue reads

typedef __attribute__((ext_vector_type(8))) _Float16 halfx8;
typedef __attribute__((ext_vector_type(8))) unsigned short ushortx8;
typedef __attribute__((ext_vector_type(4))) float floatx4;

__device__ __forceinline__ unsigned short f32_to_f16u(float x) {
    _Float16 h = (_Float16)x;                       // v_cvt_f16_f32 (RNE)
    return __builtin_bit_cast(unsigned short, h);
}
__device__ __forceinline__ float f16u_to_f32(unsigned short u) {
    _Float16 h = __builtin_bit_cast(_Float16, u);
    return (float)h;
}
__device__ __forceinline__ float fsigm(float x) {
    return __builtin_amdgcn_rcpf(1.0f + __expf(-x));
}
__device__ __forceinline__ float ftanh(float x) {
    // 1 - 2/(e^{2x}+1); exp->inf handled correctly (rcp(inf)=0)
    return 1.0f - 2.0f * __builtin_amdgcn_rcpf(1.0f + __expf(2.0f * x));
}

// ---------------------------------------------------------------------------
// Prep: pack B into MFMA B-fragment order: Bpack[tile][kc][lane][j] (8 f16 = 16B)
//   n = tile*16 + (lane&15),  k = kc*32 + (lane>>4)*8 + j      (VERIFIED in R1)
// ---------------------------------------------------------------------------
__global__ void lstm_prep_pack(const float* __restrict__ W_ih,
                               const float* __restrict__ W_hh,
                               const float* __restrict__ b_ih,
                               const float* __restrict__ b_hh,
                               ushortx8* __restrict__ Bpack) {
    int t = blockIdx.x * 256 + threadIdx.x;   // (tile,kc,lane) flattened: 25*4*64 = 6400
    if (t >= NTILE * 4 * 64) return;
    int lane = t & 63;
    int kc   = (t >> 6) & 3;
    int tile = t >> 8;
    int n  = tile * 16 + (lane & 15);
    int k0 = kc * 32 + ((lane >> 4) & 3) * 8;
    ushortx8 v;
#pragma unroll
    for (int j = 0; j < 8; ++j) {
        int k = k0 + j;
        unsigned short w = 0;
        if (k < 100) {
            w = f32_to_f16u(W_hh[n * 100 + k]);
        } else if (k < 104) {
            w = f32_to_f16u(W_ih[n * 4 + (k - 100)]);
        } else if (k < 108) {
            float wf = W_ih[n * 4 + (k - 104)];
            unsigned short hi = f32_to_f16u(wf);
            w = f32_to_f16u(wf - f16u_to_f32(hi));
        } else if (k == 108) {
            float b = b_ih[n] + b_hh[n];
            w = f32_to_f16u(b);
        } else if (k == 109) {
            float b = b_ih[n] + b_hh[n];
            unsigned short hi = f32_to_f16u(b);
            w = f32_to_f16u(b - f16u_to_f32(hi));
        }
        v[j] = w;
    }
    Bpack[t] = v;
}

// ---------------------------------------------------------------------------
// Main: one block = 16 sequences, full T loop. 4 waves; wave w owns N-tiles
// {w, w+4, ...}. B frags persist in regs (112, unified VGPR/AGPR file).
// launch_bounds(256,3): 3 blocks/CU -> all 768 blocks co-resident.
// ---------------------------------------------------------------------------
__global__ void __launch_bounds__(256, 3)
lstm_main(const float* __restrict__ x, const ushortx8* __restrict__ Bpack,
          float* __restrict__ out) {
    __shared__ __align__(16) unsigned short s_A[2 * 16 * KSTR];     //  8704 B (A_hi | A_lo)
    __shared__ __align__(16) float          s_g[NCOL * GPAD];       // 38400 B

    const int tid  = threadIdx.x;
    const int lane = tid & 63;
    const int wave = tid >> 6;
    const int seq0 = blockIdx.x * S_BLK;
    const int m    = lane & 15;
    const int quad = lane >> 4;

    // ---- B fragments: global -> regs, once
    halfx8 bfrag[7][4];
#pragma unroll
    for (int it = 0; it < 7; ++it) {
        int tile = wave + it * 4;
        if (tile < NTILE) {
#pragma unroll
            for (int kc = 0; kc < 4; ++kc)
                bfrag[it][kc] = __builtin_bit_cast(halfx8, Bpack[(tile * 4 + kc) * 64 + lane]);
        }
    }

    // refresh-thread x pointer (valid for tid < 128): (s = tid&15, cc = tid>>4)
    const int rs = tid & 15, rc = tid >> 4;
    const float* xb = x + (size_t)(seq0 + rs) * (T_STEPS * 4) + (rc & 3);

    // ---- zero A (h(0)=0; pad cols and A_lo cols 0..99 stay 0 forever)
    for (int i = tid; i < (2 * 16 * KSTR) / 2; i += 256)
        ((unsigned int*)s_A)[i] = 0u;
    float x0 = 0.0f;
    if (tid < 128) x0 = xb[0];
    __syncthreads();
    // ---- init x(t=0) cols + constant bias-select cols
    if (tid < 128) {
        unsigned short hi = f32_to_f16u(x0);
        if (rc < 4) {
            s_A[rs * KSTR + 100 + rc]        = hi;                                // A_hi = x_hi
            s_A[(16 + rs) * KSTR + 100 + rc] = f32_to_f16u(x0 - f16u_to_f32(hi)); // A_lo = x_lo
        } else {
            s_A[(16 + rs) * KSTR + 100 + rc] = hi;                                // A_lo = x_hi (W_lo rows)
        }
    } else if (tid < 144) {
        s_A[(tid - 128) * KSTR + 108] = 0x3C00;        // A_hi col108 = 1.0 (bias hi)
    } else if (tid < 160) {
        s_A[(16 + tid - 144) * KSTR + 109] = 0x3C00;   // A_lo col109 = 1.0 (bias lo)
    }

    float c_reg[6];
#pragma unroll
    for (int u = 0; u < 6; ++u) c_reg[u] = 0.0f;
    float c6 = 0.0f;

    const unsigned short* aHi  = &s_A[m * KSTR + quad * 8];
    const unsigned short* aLo3 = &s_A[(16 + m) * KSTR + quad * 8 + 96];   // kc3 of A_lo

    const int us = tid & 15;     // epilogue unit s
    const int j0 = tid >> 4;     // epilogue unit j base (j = j0 + 16u)

    for (int t = 0; t < T_STEPS; ++t) {
        // prefetch x(t+1) — issued before the MFMA phase to hide latency
        float xnext = 0.0f;
        if (tid < 128) {
            int tn = t + 1; if (tn > T_STEPS - 1) tn = T_STEPS - 1;
            xnext = xb[tn * 4];
        }
        __syncthreads();   // A(t) ready
        halfx8 ah[4], al3;
#pragma unroll
        for (int kc = 0; kc < 4; ++kc)
            ah[kc] = *(const halfx8*)(aHi + kc * 32);   // ds_read_b128
        al3 = *(const halfx8*)aLo3;                     // ds_read_b128 (kc3 lo)
#pragma unroll
        for (int it = 0; it < 7; ++it) {
            int tile = wave + it * 4;
            if (tile < NTILE) {
                floatx4 acc = {0.0f, 0.0f, 0.0f, 0.0f};
#pragma unroll
                for (int kc = 0; kc < 4; ++kc)
                    acc = __builtin_amdgcn_mfma_f32_16x16x32_f16(ah[kc], bfrag[it][kc], acc, 0, 0, 0);
                acc = __builtin_amdgcn_mfma_f32_16x16x32_f16(al3, bfrag[it][3], acc, 0, 0, 0);
                // C/D layout: col(n-within-tile) = lane&15, row(seq) = quad*4 + r
                *(floatx4*)&s_g[(tile * 16 + m) * GPAD + quad * 4] = acc;
            }
        }
        __syncthreads();   // gates ready

        const bool last = (t == T_STEPS - 1);
#pragma unroll
        for (int u = 0; u < 6; ++u) {
            int j = j0 + u * 16;              // j in 0..95, all threads unconditional
            float gi = s_g[j * GPAD + us];
            float gf = s_g[(100 + j) * GPAD + us];
            float gg = s_g[(200 + j) * GPAD + us];
            float go = s_g[(300 + j) * GPAD + us];
            float c  = fsigm(gf) * c_reg[u] + fsigm(gi) * ftanh(gg);
            c_reg[u] = c;
            float h  = fsigm(go) * ftanh(c);
            if (!last) {
                s_A[us * KSTR + j] = f32_to_f16u(h);    // h as f16 (hi only)
            } else {
                out[(size_t)(seq0 + us) * H_UNITS + j] = h;
            }
        }
        if (tid >= 192) {                     // units j = 96..99
            int d = tid - 192;
            int s = d & 15, j = 96 + (d >> 4);
            float gi = s_g[j * GPAD + s];
            float gf = s_g[(100 + j) * GPAD + s];
            float gg = s_g[(200 + j) * GPAD + s];
            float go = s_g[(300 + j) * GPAD + s];
            float c  = fsigm(gf) * c6 + fsigm(gi) * ftanh(gg);
            c6 = c;
            float h  = fsigm(go) * ftanh(c);
            if (!last) {
                s_A[s * KSTR + j] = f32_to_f16u(h);
            } else {
                out[(size_t)(seq0 + s) * H_UNITS + j] = h;
            }
        }
        if (tid < 128 && !last) {             // refresh x(t+1) cols 100..107
            unsigned short hi = f32_to_f16u(xnext);
            if (rc < 4) {
                s_A[rs * KSTR + 100 + rc]        = hi;
                s_A[(16 + rs) * KSTR + 100 + rc] = f32_to_f16u(xnext - f16u_to_f32(hi));
            } else {
                s_A[(16 + rs) * KSTR + 100 + rc] = hi;
            }
        }
    }
}

extern "C" void kernel_launch(void* const* d_in, const int* in_sizes, int n_in,
                              void* d_out, int out_size, void* d_ws, size_t ws_size,
                              hipStream_t stream) {
    const float* x    = (const float*)d_in[0];   // [4096,3,128,4]
    const float* W_ih = (const float*)d_in[1];   // [400,4]
    const float* W_hh = (const float*)d_in[2];   // [400,100]
    const float* b_ih = (const float*)d_in[3];   // [400]
    const float* b_hh = (const float*)d_in[4];   // [400]
    ushortx8* Bpack = (ushortx8*)d_ws;           // 25*4*64*16 B = 102,400 B

    lstm_prep_pack<<<25, 256, 0, stream>>>(W_ih, W_hh, b_ih, b_hh, Bpack);
    lstm_main<<<NBLK, 256, 0, stream>>>(x, Bpack, (float*)d_out);
}